// Round 10
// baseline (222.430 us; speedup 1.0000x reference)
//
#include <hip/hip_runtime.h>
#include <math.h>

// Problem constants (fixed by reference)
#define BDIM 8
#define TDIM 2048
#define CDIM 256
#define HDIM 8
#define DDIM 32
#define TP   (TDIM + 2)   // padded time (halo row above and below, zeroed)

typedef __attribute__((ext_vector_type(8))) short bf16x8;   // MFMA A/B frag (4 VGPR)
typedef __attribute__((ext_vector_type(4))) float f32x4;    // MFMA C/D frag

#if __has_builtin(__builtin_amdgcn_exp2f)
#define EXP2(x) __builtin_amdgcn_exp2f(x)
#else
#define EXP2(x) exp2f(x)
#endif

// pack two f32 -> one dword of two bf16 (round-half-up: +0x8000 then v_perm)
__device__ __forceinline__ unsigned pk2(float lo, float hi) {
    union { float f; unsigned u; } a, b;
    a.f = lo; b.f = hi;
    return __builtin_amdgcn_perm(b.u + 0x8000u, a.u + 0x8000u, 0x07060302u);
}
// truncating pack (1 op). For p >= 0 the <=0.8% downward bias cancels between
// softmax numerator and denominator (l is summed from the SAME bf16 values).
__device__ __forceinline__ unsigned pk2t(float lo, float hi) {
    union { float f; unsigned u; } a, b;
    a.f = lo; b.f = hi;
    return __builtin_amdgcn_perm(b.u, a.u, 0x07060302u);
}
__device__ __forceinline__ short bf1(float v) {
    union { float f; unsigned u; } a; a.f = v;
    return (short)((a.u + 0x8000u) >> 16);
}
// async global->LDS, 16B per lane (dest must be wave-uniform base + lane*16)
__device__ __forceinline__ void gld16(const short* g, short* l) {
    __builtin_amdgcn_global_load_lds((const __attribute__((address_space(1))) void*)g,
                                     (__attribute__((address_space(3))) void*)l, 16, 0, 0);
}

#define XBLK 832   // prep: blocks doing x-convert + halos
#define WBLK 192   // prep: blocks doing LDS-tiled weight transpose (12 pairs x 16)

// ---------------------------------------------------------------------------
// Prep: x -> bf16 padded xbfp[B][TP][C] (halos zero); weights -> bf16 W^T
// (row=co, col=k=dt*256+ci) via LDS-tiled transpose (coalesced both sides).
// ---------------------------------------------------------------------------
__global__ __launch_bounds__(256) void prep_kernel(
    const float* __restrict__ x,
    const float* __restrict__ Wq, const float* __restrict__ Wk,
    const float* __restrict__ Wv, const float* __restrict__ Wo,
    short* __restrict__ xbfp, short* __restrict__ cp,
    short* __restrict__ wcat, short* __restrict__ wot)
{
    const int tid = threadIdx.x;
    if (blockIdx.x < XBLK) {
        const int NX = BDIM * TDIM * 64;    // float4 chunks of x
        const int NH = 4096;                // halo dwords (xbfp + cp)
        unsigned* xw = (unsigned*)xbfp;
        unsigned* cw = (unsigned*)cp;
        for (int i = blockIdx.x * 256 + tid; i < NX + NH; i += XBLK * 256) {
            if (i < NX) {
                const int bt = i >> 6, c4 = i & 63;
                const int b = bt >> 11, t = bt & 2047;
                const float4 f = *(const float4*)(x + (size_t)bt * 256 + c4 * 4);
                const size_t wo_ = (size_t)(b * TP + t + 1) * 128 + c4 * 2;
                xw[wo_]     = pk2(f.x, f.y);
                xw[wo_ + 1] = pk2(f.z, f.w);
            } else {
                const int hz = i - NX;
                const int half = hz >> 11, z = hz & 2047;
                const int b = z >> 8, r = (z >> 7) & 1, wofs = z & 127;
                const size_t w_ = ((size_t)b * TP + (size_t)r * (TP - 1)) * 128 + wofs;
                if (half == 0) xw[w_] = 0u; else cw[w_] = 0u;
            }
        }
    } else {
        // weight transpose: 12 (dt,mat) pairs x 16 subtiles of 64ci x 64co
        __shared__ float xs[64][65];
        const int wb = blockIdx.x - XBLK;
        const int pair = wb >> 4, sub = wb & 15;
        const int dt = pair >> 2, mat = pair & 3;        // mat: 0=q 1=k 2=v 3=o
        const int ci0 = (sub >> 2) * 64, co0 = (sub & 3) * 64;
        const float* W = mat == 0 ? Wq : mat == 1 ? Wk : mat == 2 ? Wv : Wo;
        const float* src = W + dt * 65536 + (size_t)ci0 * 256 + co0;
        for (int idx = tid; idx < 4096; idx += 256) {
            const int r = idx >> 6, c = idx & 63;
            xs[r][c] = src[(size_t)r * 256 + c];
        }
        __syncthreads();
        short* dstbase = (mat < 3) ? (wcat + (size_t)(mat * 256 + co0) * 768)
                                   : (wot + (size_t)co0 * 768);
        for (int idx = tid; idx < 512; idx += 256) {
            const int co_l = idx >> 3, ci_l = (idx & 7) * 8;
            uint4 u;
            u.x = pk2(xs[ci_l + 0][co_l], xs[ci_l + 1][co_l]);
            u.y = pk2(xs[ci_l + 2][co_l], xs[ci_l + 3][co_l]);
            u.z = pk2(xs[ci_l + 4][co_l], xs[ci_l + 5][co_l]);
            u.w = pk2(xs[ci_l + 6][co_l], xs[ci_l + 7][co_l]);
            *(uint4*)(dstbase + (size_t)co_l * 768 + dt * 256 + ci0 + ci_l) = u;
        }
    }
}

// ---------------------------------------------------------------------------
// QKV conv as double-buffered MFMA GEMM (m97 structure).
// Result transposed: A = W rows (m=co_cat), B = x rows (n=t).
// Block 256 thr = 4 waves; tile 128 co x 128 t; BK=32. grid (128, 6).
// V-epilogue: R6/R8 direct scatter stores (known-good; the LDS-transpose
// variant is CONVICTED by the R7/R9 failures — do not re-land it).
// ---------------------------------------------------------------------------
__global__ __launch_bounds__(256) void gemm_qkv(
    const short* __restrict__ xbfp, const short* __restrict__ wcat,
    const float* __restrict__ bq, const float* __restrict__ bk,
    const float* __restrict__ bv,
    short* __restrict__ qo, short* __restrict__ ko, short* __restrict__ vt2)
{
    __shared__ short As[2][4096];
    __shared__ short Bs[2][4096];
    const int tid = threadIdx.x;
    const int wv = tid >> 6, lane = tid & 63, quad = lane >> 4, col = lane & 15;
    const int bx = blockIdx.x;
    const int b = bx >> 4, t0 = (bx & 15) * 128;
    const int by = blockIdx.y;
    const int qkv = by >> 1;
    const int m0 = by * 128;

    const short* wA = wcat + (size_t)m0 * 768;
    const short* xB = xbfp + ((size_t)b * TP + t0) * CDIM;
    const int r0 = tid >> 2, s0 = (tid & 3) * 8;   // chunk row / in-row offset

#define STAGE_Q(kk, bsel) do {                                                  \
    const int dt_ = (kk) >> 3, ci0_ = ((kk) & 7) * 32, k0_ = (kk) * 32;         \
    gld16(wA + (size_t)r0 * 768 + k0_ + s0,        &As[bsel][tid * 8]);         \
    gld16(wA + (size_t)(r0 + 64) * 768 + k0_ + s0, &As[bsel][tid * 8 + 2048]);  \
    gld16(xB + (size_t)(r0 + dt_) * 256 + ci0_ + s0,      &Bs[bsel][tid * 8]);  \
    gld16(xB + (size_t)(r0 + 64 + dt_) * 256 + ci0_ + s0, &Bs[bsel][tid * 8 + 2048]); \
} while (0)

    STAGE_Q(0, 0);

    const float* bias = qkv == 0 ? bq : qkv == 1 ? bk : bv;
    f32x4 acc[4][4];
#pragma unroll
    for (int mt = 0; mt < 4; ++mt) {
        const int cb = ((m0 + (wv & 1) * 64 + mt * 16) & 255) + quad * 4;
        const float4 b4 = *(const float4*)(bias + cb);
#pragma unroll
        for (int nt = 0; nt < 4; ++nt) acc[mt][nt] = (f32x4){b4.x, b4.y, b4.z, b4.w};
    }

    int bsel = 0;
    for (int kk = 0; kk < 24; ++kk) {
        __syncthreads();
        if (kk < 23) STAGE_Q(kk + 1, bsel ^ 1);
        const short* Ab = &As[bsel][((wv & 1) * 64 + col) * 32 + quad * 8];
        const short* Bb = &Bs[bsel][((wv >> 1) * 64 + col) * 32 + quad * 8];
        bf16x8 af[4], bfr[4];
#pragma unroll
        for (int i = 0; i < 4; ++i) {
            af[i]  = *(const bf16x8*)(Ab + i * 512);
            bfr[i] = *(const bf16x8*)(Bb + i * 512);
        }
#pragma unroll
        for (int mt = 0; mt < 4; ++mt)
#pragma unroll
            for (int nt = 0; nt < 4; ++nt)
                acc[mt][nt] = __builtin_amdgcn_mfma_f32_16x16x32_bf16(af[mt], bfr[nt], acc[mt][nt], 0, 0, 0);
        bsel ^= 1;
    }

    const float qs = 0.25503000508221157f;   // log2(e)/sqrt(32)
#pragma unroll
    for (int mt = 0; mt < 4; ++mt) {
        const int cocat = m0 + (wv & 1) * 64 + mt * 16 + quad * 4;
        const int co = cocat & 255;
        const int hh = co >> 5, d = co & 31;
        const size_t bh = (size_t)b * HDIM + hh;
#pragma unroll
        for (int nt = 0; nt < 4; ++nt) {
            const int t = t0 + (wv >> 1) * 64 + nt * 16 + col;
            const f32x4 a = acc[mt][nt];
            if (qkv == 0) {
                uint2 u = make_uint2(pk2(a[0] * qs, a[1] * qs), pk2(a[2] * qs, a[3] * qs));
                *(uint2*)(qo + (bh * TDIM + t) * DDIM + d) = u;
            } else if (qkv == 1) {
                uint2 u = make_uint2(pk2(a[0], a[1]), pk2(a[2], a[3]));
                *(uint2*)(ko + (bh * TDIM + t) * DDIM + d) = u;
            } else {
                const int kt = t >> 6, u6 = t & 63, kg = u6 >> 5, rr = u6 & 31;
                const int j = ((rr >> 4) << 2) | (rr & 3), qd = (rr >> 2) & 3;
                short* vb2 = vt2 + ((bh * 32 + kt) * 2 + kg) * 1024 + qd * 8 + j;
#pragma unroll
                for (int r = 0; r < 4; ++r) vb2[(d + r) * 32] = bf1(a[r]);
            }
        }
    }
#undef STAGE_Q
}

// ---------------------------------------------------------------------------
// Output conv + residual, same GEMM structure. A = Wot rows (m=co, M=256),
// B = ctx rows from padded cp (n=t). grid (128, 2). out = x + acc (+bo).
// ---------------------------------------------------------------------------
__global__ __launch_bounds__(256) void gemm_res(
    const short* __restrict__ cp, const short* __restrict__ wot,
    const float* __restrict__ bo, const float* __restrict__ x,
    float* __restrict__ out)
{
    __shared__ short As[2][4096];
    __shared__ short Bs[2][4096];
    const int tid = threadIdx.x;
    const int wv = tid >> 6, lane = tid & 63, quad = lane >> 4, col = lane & 15;
    const int bx = blockIdx.x;
    const int b = bx >> 4, t0 = (bx & 15) * 128;
    const int m0 = blockIdx.y * 128;

    const short* wA = wot + (size_t)m0 * 768;
    const short* cB = cp + ((size_t)b * TP + t0) * CDIM;
    const int r0 = tid >> 2, s0 = (tid & 3) * 8;

#define STAGE_R(kk, bsel) do {                                                  \
    const int dt_ = (kk) >> 3, ci0_ = ((kk) & 7) * 32, k0_ = (kk) * 32;         \
    gld16(wA + (size_t)r0 * 768 + k0_ + s0,        &As[bsel][tid * 8]);         \
    gld16(wA + (size_t)(r0 + 64) * 768 + k0_ + s0, &As[bsel][tid * 8 + 2048]);  \
    gld16(cB + (size_t)(r0 + dt_) * 256 + ci0_ + s0,      &Bs[bsel][tid * 8]);  \
    gld16(cB + (size_t)(r0 + 64 + dt_) * 256 + ci0_ + s0, &Bs[bsel][tid * 8 + 2048]); \
} while (0)

    STAGE_R(0, 0);

    f32x4 acc[4][4];
#pragma unroll
    for (int mt = 0; mt < 4; ++mt) {
        const int cb = m0 + (wv & 1) * 64 + mt * 16 + quad * 4;
        const float4 b4 = *(const float4*)(bo + cb);
#pragma unroll
        for (int nt = 0; nt < 4; ++nt) acc[mt][nt] = (f32x4){b4.x, b4.y, b4.z, b4.w};
    }

    int bsel = 0;
    for (int kk = 0; kk < 24; ++kk) {
        __syncthreads();
        if (kk < 23) STAGE_R(kk + 1, bsel ^ 1);
        const short* Ab = &As[bsel][((wv & 1) * 64 + col) * 32 + quad * 8];
        const short* Bb = &Bs[bsel][((wv >> 1) * 64 + col) * 32 + quad * 8];
        bf16x8 af[4], bfr[4];
#pragma unroll
        for (int i = 0; i < 4; ++i) {
            af[i]  = *(const bf16x8*)(Ab + i * 512);
            bfr[i] = *(const bf16x8*)(Bb + i * 512);
        }
#pragma unroll
        for (int mt = 0; mt < 4; ++mt)
#pragma unroll
            for (int nt = 0; nt < 4; ++nt)
                acc[mt][nt] = __builtin_amdgcn_mfma_f32_16x16x32_bf16(af[mt], bfr[nt], acc[mt][nt], 0, 0, 0);
        bsel ^= 1;
    }

#pragma unroll
    for (int mt = 0; mt < 4; ++mt) {
        const int co = m0 + (wv & 1) * 64 + mt * 16 + quad * 4;
#pragma unroll
        for (int nt = 0; nt < 4; ++nt) {
            const int t = t0 + (wv >> 1) * 64 + nt * 16 + col;
            const size_t o = ((size_t)b * TDIM + t) * CDIM + co;
            const float4 xv = *(const float4*)(x + o);
            const f32x4 a = acc[mt][nt];
            *(float4*)(out + o) = make_float4(a[0] + xv.x, a[1] + xv.y, a[2] + xv.z, a[3] + xv.w);
        }
    }
#undef STAGE_R
}

// ---------------------------------------------------------------------------
// MFMA flash attention, LDS double-buffered via explicit loads + ds_write
// (R8-proven staging, UNSWIZZLED — one change at a time). R10: 64-row q-tiles
// (1 q-frag/wave) -> grid (64,32) = 2048 blocks = 32 waves/CU so the
// exp-dominated VALU stream overlaps across 8 waves/SIMD instead of 4.
// S^T trick (A=K, B=Q): exp'd scores feed the PV B-operand from the lane's
// own registers (sigma(quad*8+j) = (j>>2)*16+quad*4+(j&3)); V pre-arranged so
// each PV A-frag is one b128 read; l via ones-A-frag MFMA; raw v_exp_f32
// (q pre-scaled by log2e/sqrt(D)). Grid (bh, qtile): 1-XCD K/V locality.
// ---------------------------------------------------------------------------
__global__ __launch_bounds__(256, 8) void attn_kernel(
    const short* __restrict__ q, const short* __restrict__ k,
    const short* __restrict__ vt2, short* __restrict__ cp)
{
    __shared__ short ks[2][2048];
    __shared__ short vs[2][2048];
    const int tid = threadIdx.x;
    const int wv = tid >> 6, lane = tid & 63, quad = lane >> 4, col = lane & 15;
    const int bh = blockIdx.x;                    // XCD-locality: bh fixes XCD
    const int q0 = blockIdx.y * 64 + wv * 16;

    const short* qb = q + (size_t)bh * TDIM * DDIM;
    const short* kb = k + (size_t)bh * TDIM * DDIM;
    const short* vb = vt2 + (size_t)bh * TDIM * DDIM;
    const int so = tid * 8;                       // staging offset (shorts)

    // stage tile 0 (regs -> LDS)
    {
        uint4 kr = *(const uint4*)(kb + so);
        uint4 vr = *(const uint4*)(vb + so);
        *(uint4*)&ks[0][so] = kr;
        *(uint4*)&vs[0][so] = vr;
    }

    const bf16x8 qf = *(const bf16x8*)(qb + (size_t)(q0 + col) * DDIM + quad * 8);

    f32x4 acc0 = {0.f, 0.f, 0.f, 0.f};
    f32x4 acc1 = {0.f, 0.f, 0.f, 0.f};
    f32x4 accl = {0.f, 0.f, 0.f, 0.f};   // ones-row: l in every reg
    const f32x4 zero = {0.f, 0.f, 0.f, 0.f};
    const short one_bf = (short)0x3F80;   // bf16 1.0
    const bf16x8 ones = {one_bf, one_bf, one_bf, one_bf, one_bf, one_bf, one_bf, one_bf};

    const int foff = col * 32 + quad * 8;         // frag offset within tile
    __syncthreads();                              // tile 0 visible

#pragma unroll 2
    for (int kt = 0; kt < TDIM / 64; ++kt) {
        const int cur = kt & 1;
        // issue next tile's global loads FIRST (hidden under compute below)
        uint4 krn, vrn;
        const bool more = kt < TDIM / 64 - 1;
        if (more) {
            krn = *(const uint4*)(kb + (kt + 1) * 2048 + so);
            vrn = *(const uint4*)(vb + (kt + 1) * 2048 + so);
        }
        bf16x8 kc[4], vf[4];
#pragma unroll
        for (int g = 0; g < 4; ++g) {
            kc[g] = *(const bf16x8*)&ks[cur][g * 512 + foff];
            vf[g] = *(const bf16x8*)&vs[cur][g * 512 + foff];
        }
        f32x4 s[4];
#pragma unroll
        for (int g = 0; g < 4; ++g)
            s[g] = __builtin_amdgcn_mfma_f32_16x16x32_bf16(kc[g], qf, zero, 0, 0, 0);
        float p[16];
#pragma unroll
        for (int g = 0; g < 4; ++g)
#pragma unroll
            for (int r = 0; r < 4; ++r)
                p[g * 4 + r] = EXP2(s[g][r]);
        union { unsigned u[4]; bf16x8 v; } P0, P1;
        P0.u[0] = pk2t(p[0], p[1]);   P0.u[1] = pk2t(p[2], p[3]);
        P0.u[2] = pk2t(p[4], p[5]);   P0.u[3] = pk2t(p[6], p[7]);
        P1.u[0] = pk2t(p[8], p[9]);   P1.u[1] = pk2t(p[10], p[11]);
        P1.u[2] = pk2t(p[12], p[13]); P1.u[3] = pk2t(p[14], p[15]);
        acc0 = __builtin_amdgcn_mfma_f32_16x16x32_bf16(vf[0], P0.v, acc0, 0, 0, 0);
        acc1 = __builtin_amdgcn_mfma_f32_16x16x32_bf16(vf[1], P0.v, acc1, 0, 0, 0);
        accl = __builtin_amdgcn_mfma_f32_16x16x32_bf16(ones,  P0.v, accl, 0, 0, 0);
        acc0 = __builtin_amdgcn_mfma_f32_16x16x32_bf16(vf[2], P1.v, acc0, 0, 0, 0);
        acc1 = __builtin_amdgcn_mfma_f32_16x16x32_bf16(vf[3], P1.v, acc1, 0, 0, 0);
        accl = __builtin_amdgcn_mfma_f32_16x16x32_bf16(ones,  P1.v, accl, 0, 0, 0);
        if (more) {
            *(uint4*)&ks[cur ^ 1][so] = krn;
            *(uint4*)&vs[cur ^ 1][so] = vrn;
        }
        __syncthreads();   // seals tile-(kt+1) writes; all reads of cur done
    }

    const int b = bh >> 3, hh = bh & 7;
    {
        const float inv = 1.f / accl[0];   // full-key sum, identical in all regs
        const int t = q0 + col;
        short* crow = cp + ((size_t)b * TP + t + 1) * CDIM + hh * DDIM;
        uint2 u0 = make_uint2(pk2(acc0[0] * inv, acc0[1] * inv),
                              pk2(acc0[2] * inv, acc0[3] * inv));
        uint2 u1 = make_uint2(pk2(acc1[0] * inv, acc1[1] * inv),
                              pk2(acc1[2] * inv, acc1[3] * inv));
        *(uint2*)(crow + quad * 4)      = u0;
        *(uint2*)(crow + 16 + quad * 4) = u1;
    }
}

// ---------------------------------------------------------------------------
extern "C" void kernel_launch(void* const* d_in, const int* in_sizes, int n_in,
                              void* d_out, int out_size, void* d_ws, size_t ws_size,
                              hipStream_t stream) {
    const float* x  = (const float*)d_in[0];
    const float* Wq = (const float*)d_in[1];
    const float* bq = (const float*)d_in[2];
    const float* Wk = (const float*)d_in[3];
    const float* bk = (const float*)d_in[4];
    const float* Wv = (const float*)d_in[5];
    const float* bv = (const float*)d_in[6];
    const float* Wo = (const float*)d_in[7];
    const float* bo = (const float*)d_in[8];
    float* out = (float*)d_out;

    short* p = (short*)d_ws;
    short* xbfp = p; p += (size_t)BDIM * TP * CDIM;        // 4,198,400
    short* cpb  = p; p += (size_t)BDIM * TP * CDIM;        // 4,198,400
    short* qbuf = p; p += (size_t)BDIM * HDIM * TDIM * DDIM; // 4,194,304
    short* kbuf = p; p += (size_t)BDIM * HDIM * TDIM * DDIM;
    short* vt2  = p; p += (size_t)BDIM * HDIM * TDIM * DDIM;
    short* wcat = p; p += 768 * 768;
    short* wot  = p; p += 256 * 768;
    // total ~43.5 MB

    prep_kernel<<<dim3(XBLK + WBLK), 256, 0, stream>>>(x, Wq, Wk, Wv, Wo, xbfp, cpb, wcat, wot);
    gemm_qkv<<<dim3(128, 6), 256, 0, stream>>>(xbfp, wcat, bq, bk, bv, qbuf, kbuf, vt2);
    attn_kernel<<<dim3(64, 32), 256, 0, stream>>>(qbuf, kbuf, vt2, cpb);
    gemm_res<<<dim3(128, 2), 256, 0, stream>>>(cpb, wot, bo, x, out);
}

// Round 11
// 186.476 us; speedup vs baseline: 1.1928x; 1.1928x over previous
//
#include <hip/hip_runtime.h>
#include <math.h>

// Problem constants (fixed by reference)
#define BDIM 8
#define TDIM 2048
#define CDIM 256
#define HDIM 8
#define DDIM 32
#define TP   (TDIM + 2)   // padded time (halo row above and below, zeroed)

// attention LDS tile: 64 rows x 36 shorts (pad 32->36: 18-dword row stride
// spreads the 16 col-lanes of a frag read over 16 distinct even bank-starts)
#define LROW 36
#define LTILE (64 * LROW)   // 2304 shorts

typedef __attribute__((ext_vector_type(8))) short bf16x8;   // MFMA A/B frag (4 VGPR)
typedef __attribute__((ext_vector_type(4))) float f32x4;    // MFMA C/D frag

#if __has_builtin(__builtin_amdgcn_exp2f)
#define EXP2(x) __builtin_amdgcn_exp2f(x)
#else
#define EXP2(x) exp2f(x)
#endif

// pack two f32 -> one dword of two bf16 (round-half-up: +0x8000 then v_perm)
__device__ __forceinline__ unsigned pk2(float lo, float hi) {
    union { float f; unsigned u; } a, b;
    a.f = lo; b.f = hi;
    return __builtin_amdgcn_perm(b.u + 0x8000u, a.u + 0x8000u, 0x07060302u);
}
// truncating pack (1 op). For p >= 0 the <=0.8% downward bias cancels between
// softmax numerator and denominator (l is summed from the SAME bf16 values).
__device__ __forceinline__ unsigned pk2t(float lo, float hi) {
    union { float f; unsigned u; } a, b;
    a.f = lo; b.f = hi;
    return __builtin_amdgcn_perm(b.u, a.u, 0x07060302u);
}
__device__ __forceinline__ short bf1(float v) {
    union { float f; unsigned u; } a; a.f = v;
    return (short)((a.u + 0x8000u) >> 16);
}
// async global->LDS, 16B per lane (dest must be wave-uniform base + lane*16)
__device__ __forceinline__ void gld16(const short* g, short* l) {
    __builtin_amdgcn_global_load_lds((const __attribute__((address_space(1))) void*)g,
                                     (__attribute__((address_space(3))) void*)l, 16, 0, 0);
}

#define XBLK 832   // prep: blocks doing x-convert + halos
#define WBLK 192   // prep: blocks doing LDS-tiled weight transpose (12 pairs x 16)

// ---------------------------------------------------------------------------
// Prep: x -> bf16 padded xbfp[B][TP][C] (halos zero); weights -> bf16 W^T
// (row=co, col=k=dt*256+ci) via LDS-tiled transpose (coalesced both sides).
// ---------------------------------------------------------------------------
__global__ __launch_bounds__(256) void prep_kernel(
    const float* __restrict__ x,
    const float* __restrict__ Wq, const float* __restrict__ Wk,
    const float* __restrict__ Wv, const float* __restrict__ Wo,
    short* __restrict__ xbfp, short* __restrict__ cp,
    short* __restrict__ wcat, short* __restrict__ wot)
{
    const int tid = threadIdx.x;
    if (blockIdx.x < XBLK) {
        const int NX = BDIM * TDIM * 64;    // float4 chunks of x
        const int NH = 4096;                // halo dwords (xbfp + cp)
        unsigned* xw = (unsigned*)xbfp;
        unsigned* cw = (unsigned*)cp;
        for (int i = blockIdx.x * 256 + tid; i < NX + NH; i += XBLK * 256) {
            if (i < NX) {
                const int bt = i >> 6, c4 = i & 63;
                const int b = bt >> 11, t = bt & 2047;
                const float4 f = *(const float4*)(x + (size_t)bt * 256 + c4 * 4);
                const size_t wo_ = (size_t)(b * TP + t + 1) * 128 + c4 * 2;
                xw[wo_]     = pk2(f.x, f.y);
                xw[wo_ + 1] = pk2(f.z, f.w);
            } else {
                const int hz = i - NX;
                const int half = hz >> 11, z = hz & 2047;
                const int b = z >> 8, r = (z >> 7) & 1, wofs = z & 127;
                const size_t w_ = ((size_t)b * TP + (size_t)r * (TP - 1)) * 128 + wofs;
                if (half == 0) xw[w_] = 0u; else cw[w_] = 0u;
            }
        }
    } else {
        // weight transpose: 12 (dt,mat) pairs x 16 subtiles of 64ci x 64co
        __shared__ float xs[64][65];
        const int wb = blockIdx.x - XBLK;
        const int pair = wb >> 4, sub = wb & 15;
        const int dt = pair >> 2, mat = pair & 3;        // mat: 0=q 1=k 2=v 3=o
        const int ci0 = (sub >> 2) * 64, co0 = (sub & 3) * 64;
        const float* W = mat == 0 ? Wq : mat == 1 ? Wk : mat == 2 ? Wv : Wo;
        const float* src = W + dt * 65536 + (size_t)ci0 * 256 + co0;
        for (int idx = tid; idx < 4096; idx += 256) {
            const int r = idx >> 6, c = idx & 63;
            xs[r][c] = src[(size_t)r * 256 + c];
        }
        __syncthreads();
        short* dstbase = (mat < 3) ? (wcat + (size_t)(mat * 256 + co0) * 768)
                                   : (wot + (size_t)co0 * 768);
        for (int idx = tid; idx < 512; idx += 256) {
            const int co_l = idx >> 3, ci_l = (idx & 7) * 8;
            uint4 u;
            u.x = pk2(xs[ci_l + 0][co_l], xs[ci_l + 1][co_l]);
            u.y = pk2(xs[ci_l + 2][co_l], xs[ci_l + 3][co_l]);
            u.z = pk2(xs[ci_l + 4][co_l], xs[ci_l + 5][co_l]);
            u.w = pk2(xs[ci_l + 6][co_l], xs[ci_l + 7][co_l]);
            *(uint4*)(dstbase + (size_t)co_l * 768 + dt * 256 + ci0 + ci_l) = u;
        }
    }
}

// ---------------------------------------------------------------------------
// QKV conv as double-buffered MFMA GEMM (m97 structure).
// Result transposed: A = W rows (m=co_cat), B = x rows (n=t).
// Block 256 thr = 4 waves; tile 128 co x 128 t; BK=32. grid (128, 6).
// V-epilogue: R6/R8 direct scatter stores (known-good; the LDS-transpose
// variant is CONVICTED by the R7/R9 failures — do not re-land it).
// ---------------------------------------------------------------------------
__global__ __launch_bounds__(256) void gemm_qkv(
    const short* __restrict__ xbfp, const short* __restrict__ wcat,
    const float* __restrict__ bq, const float* __restrict__ bk,
    const float* __restrict__ bv,
    short* __restrict__ qo, short* __restrict__ ko, short* __restrict__ vt2)
{
    __shared__ short As[2][4096];
    __shared__ short Bs[2][4096];
    const int tid = threadIdx.x;
    const int wv = tid >> 6, lane = tid & 63, quad = lane >> 4, col = lane & 15;
    const int bx = blockIdx.x;
    const int b = bx >> 4, t0 = (bx & 15) * 128;
    const int by = blockIdx.y;
    const int qkv = by >> 1;
    const int m0 = by * 128;

    const short* wA = wcat + (size_t)m0 * 768;
    const short* xB = xbfp + ((size_t)b * TP + t0) * CDIM;
    const int r0 = tid >> 2, s0 = (tid & 3) * 8;   // chunk row / in-row offset

#define STAGE_Q(kk, bsel) do {                                                  \
    const int dt_ = (kk) >> 3, ci0_ = ((kk) & 7) * 32, k0_ = (kk) * 32;         \
    gld16(wA + (size_t)r0 * 768 + k0_ + s0,        &As[bsel][tid * 8]);         \
    gld16(wA + (size_t)(r0 + 64) * 768 + k0_ + s0, &As[bsel][tid * 8 + 2048]);  \
    gld16(xB + (size_t)(r0 + dt_) * 256 + ci0_ + s0,      &Bs[bsel][tid * 8]);  \
    gld16(xB + (size_t)(r0 + 64 + dt_) * 256 + ci0_ + s0, &Bs[bsel][tid * 8 + 2048]); \
} while (0)

    STAGE_Q(0, 0);

    const float* bias = qkv == 0 ? bq : qkv == 1 ? bk : bv;
    f32x4 acc[4][4];
#pragma unroll
    for (int mt = 0; mt < 4; ++mt) {
        const int cb = ((m0 + (wv & 1) * 64 + mt * 16) & 255) + quad * 4;
        const float4 b4 = *(const float4*)(bias + cb);
#pragma unroll
        for (int nt = 0; nt < 4; ++nt) acc[mt][nt] = (f32x4){b4.x, b4.y, b4.z, b4.w};
    }

    int bsel = 0;
    for (int kk = 0; kk < 24; ++kk) {
        __syncthreads();
        if (kk < 23) STAGE_Q(kk + 1, bsel ^ 1);
        const short* Ab = &As[bsel][((wv & 1) * 64 + col) * 32 + quad * 8];
        const short* Bb = &Bs[bsel][((wv >> 1) * 64 + col) * 32 + quad * 8];
        bf16x8 af[4], bfr[4];
#pragma unroll
        for (int i = 0; i < 4; ++i) {
            af[i]  = *(const bf16x8*)(Ab + i * 512);
            bfr[i] = *(const bf16x8*)(Bb + i * 512);
        }
#pragma unroll
        for (int mt = 0; mt < 4; ++mt)
#pragma unroll
            for (int nt = 0; nt < 4; ++nt)
                acc[mt][nt] = __builtin_amdgcn_mfma_f32_16x16x32_bf16(af[mt], bfr[nt], acc[mt][nt], 0, 0, 0);
        bsel ^= 1;
    }

    const float qs = 0.25503000508221157f;   // log2(e)/sqrt(32)
#pragma unroll
    for (int mt = 0; mt < 4; ++mt) {
        const int cocat = m0 + (wv & 1) * 64 + mt * 16 + quad * 4;
        const int co = cocat & 255;
        const int hh = co >> 5, d = co & 31;
        const size_t bh = (size_t)b * HDIM + hh;
#pragma unroll
        for (int nt = 0; nt < 4; ++nt) {
            const int t = t0 + (wv >> 1) * 64 + nt * 16 + col;
            const f32x4 a = acc[mt][nt];
            if (qkv == 0) {
                uint2 u = make_uint2(pk2(a[0] * qs, a[1] * qs), pk2(a[2] * qs, a[3] * qs));
                *(uint2*)(qo + (bh * TDIM + t) * DDIM + d) = u;
            } else if (qkv == 1) {
                uint2 u = make_uint2(pk2(a[0], a[1]), pk2(a[2], a[3]));
                *(uint2*)(ko + (bh * TDIM + t) * DDIM + d) = u;
            } else {
                const int kt = t >> 6, u6 = t & 63, kg = u6 >> 5, rr = u6 & 31;
                const int j = ((rr >> 4) << 2) | (rr & 3), qd = (rr >> 2) & 3;
                short* vb2 = vt2 + ((bh * 32 + kt) * 2 + kg) * 1024 + qd * 8 + j;
#pragma unroll
                for (int r = 0; r < 4; ++r) vb2[(d + r) * 32] = bf1(a[r]);
            }
        }
    }
#undef STAGE_Q
}

// ---------------------------------------------------------------------------
// Output conv + residual, same GEMM structure. A = Wot rows (m=co, M=256),
// B = ctx rows from padded cp (n=t). grid (128, 2). out = x + acc (+bo).
// ---------------------------------------------------------------------------
__global__ __launch_bounds__(256) void gemm_res(
    const short* __restrict__ cp, const short* __restrict__ wot,
    const float* __restrict__ bo, const float* __restrict__ x,
    float* __restrict__ out)
{
    __shared__ short As[2][4096];
    __shared__ short Bs[2][4096];
    const int tid = threadIdx.x;
    const int wv = tid >> 6, lane = tid & 63, quad = lane >> 4, col = lane & 15;
    const int bx = blockIdx.x;
    const int b = bx >> 4, t0 = (bx & 15) * 128;
    const int m0 = blockIdx.y * 128;

    const short* wA = wot + (size_t)m0 * 768;
    const short* cB = cp + ((size_t)b * TP + t0) * CDIM;
    const int r0 = tid >> 2, s0 = (tid & 3) * 8;

#define STAGE_R(kk, bsel) do {                                                  \
    const int dt_ = (kk) >> 3, ci0_ = ((kk) & 7) * 32, k0_ = (kk) * 32;         \
    gld16(wA + (size_t)r0 * 768 + k0_ + s0,        &As[bsel][tid * 8]);         \
    gld16(wA + (size_t)(r0 + 64) * 768 + k0_ + s0, &As[bsel][tid * 8 + 2048]);  \
    gld16(cB + (size_t)(r0 + dt_) * 256 + ci0_ + s0,      &Bs[bsel][tid * 8]);  \
    gld16(cB + (size_t)(r0 + 64 + dt_) * 256 + ci0_ + s0, &Bs[bsel][tid * 8 + 2048]); \
} while (0)

    STAGE_R(0, 0);

    f32x4 acc[4][4];
#pragma unroll
    for (int mt = 0; mt < 4; ++mt) {
        const int cb = m0 + (wv & 1) * 64 + mt * 16 + quad * 4;
        const float4 b4 = *(const float4*)(bo + cb);
#pragma unroll
        for (int nt = 0; nt < 4; ++nt) acc[mt][nt] = (f32x4){b4.x, b4.y, b4.z, b4.w};
    }

    int bsel = 0;
    for (int kk = 0; kk < 24; ++kk) {
        __syncthreads();
        if (kk < 23) STAGE_R(kk + 1, bsel ^ 1);
        const short* Ab = &As[bsel][((wv & 1) * 64 + col) * 32 + quad * 8];
        const short* Bb = &Bs[bsel][((wv >> 1) * 64 + col) * 32 + quad * 8];
        bf16x8 af[4], bfr[4];
#pragma unroll
        for (int i = 0; i < 4; ++i) {
            af[i]  = *(const bf16x8*)(Ab + i * 512);
            bfr[i] = *(const bf16x8*)(Bb + i * 512);
        }
#pragma unroll
        for (int mt = 0; mt < 4; ++mt)
#pragma unroll
            for (int nt = 0; nt < 4; ++nt)
                acc[mt][nt] = __builtin_amdgcn_mfma_f32_16x16x32_bf16(af[mt], bfr[nt], acc[mt][nt], 0, 0, 0);
        bsel ^= 1;
    }

#pragma unroll
    for (int mt = 0; mt < 4; ++mt) {
        const int co = m0 + (wv & 1) * 64 + mt * 16 + quad * 4;
#pragma unroll
        for (int nt = 0; nt < 4; ++nt) {
            const int t = t0 + (wv >> 1) * 64 + nt * 16 + col;
            const size_t o = ((size_t)b * TDIM + t) * CDIM + co;
            const float4 xv = *(const float4*)(x + o);
            const f32x4 a = acc[mt][nt];
            *(float4*)(out + o) = make_float4(a[0] + xv.x, a[1] + xv.y, a[2] + xv.z, a[3] + xv.w);
        }
    }
#undef STAGE_R
}

// ---------------------------------------------------------------------------
// MFMA flash attention = R8-proven structure (32 q-rows/wave, 2 q-frags,
// grid (bh=64, qtile=16), explicit load + ds_write double-buffer) with ONE
// change: LDS rows padded 32 -> 36 shorts. R8 counters showed 4.19M
// SQ_LDS_BANK_CONFLICT cycles from the stride-64B frag reads (per 32-lane
// phase only 2 distinct granule-starts -> 8-way). 18-dword row stride gives
// 16 distinct even bank-starts (uniform 8 touches/bank = b128 minimum) and
// halves staging-write aliasing to the free 2-way.
// S^T trick (A=K, B=Q): exp'd scores feed the PV B-operand from the lane's
// own registers (sigma(quad*8+j) = (j>>2)*16+quad*4+(j&3)); V pre-arranged so
// each PV A-frag is one b128 read; l via ones-A-frag MFMA; raw v_exp_f32
// (q pre-scaled by log2e/sqrt(D)). Do NOT shrink q-tiles (R10: 2x staging
// traffic + L2 thrash, 52.6 -> 91 µs) or swizzle/DMA-stage (R7/R9 failures).
// ---------------------------------------------------------------------------
__global__ __launch_bounds__(256, 4) void attn_kernel(
    const short* __restrict__ q, const short* __restrict__ k,
    const short* __restrict__ vt2, short* __restrict__ cp)
{
    __shared__ short ks[2][LTILE];
    __shared__ short vs[2][LTILE];
    const int tid = threadIdx.x;
    const int wv = tid >> 6, lane = tid & 63, quad = lane >> 4, col = lane & 15;
    const int bh = blockIdx.x;                    // XCD-locality: bh fixes XCD
    const int q0 = blockIdx.y * 128 + wv * 32;

    const short* qb = q + (size_t)bh * TDIM * DDIM;
    const short* kb = k + (size_t)bh * TDIM * DDIM;
    const short* vb = vt2 + (size_t)bh * TDIM * DDIM;
    const int soG = tid * 8;                               // global (shorts)
    const int soW = (tid >> 2) * LROW + (tid & 3) * 8;     // padded LDS row

    // stage tile 0 (regs -> LDS)
    {
        uint4 kr = *(const uint4*)(kb + soG);
        uint4 vr = *(const uint4*)(vb + soG);
        *(uint4*)&ks[0][soW] = kr;
        *(uint4*)&vs[0][soW] = vr;
    }

    bf16x8 qf[2];
    qf[0] = *(const bf16x8*)(qb + (size_t)(q0 + col) * DDIM + quad * 8);
    qf[1] = *(const bf16x8*)(qb + (size_t)(q0 + 16 + col) * DDIM + quad * 8);

    f32x4 acc0[2] = {{0.f,0.f,0.f,0.f},{0.f,0.f,0.f,0.f}};
    f32x4 acc1[2] = {{0.f,0.f,0.f,0.f},{0.f,0.f,0.f,0.f}};
    f32x4 accl[2] = {{0.f,0.f,0.f,0.f},{0.f,0.f,0.f,0.f}};   // ones-row: l in every reg
    const f32x4 zero = {0.f, 0.f, 0.f, 0.f};
    const short one_bf = (short)0x3F80;   // bf16 1.0
    const bf16x8 ones = {one_bf, one_bf, one_bf, one_bf, one_bf, one_bf, one_bf, one_bf};

    const int foff = col * LROW + quad * 8;       // frag offset within padded tile
    __syncthreads();                              // tile 0 visible

#pragma unroll 2
    for (int kt = 0; kt < TDIM / 64; ++kt) {
        const int cur = kt & 1;
        // issue next tile's global loads FIRST (hidden under compute below)
        uint4 krn, vrn;
        const bool more = kt < TDIM / 64 - 1;
        if (more) {
            krn = *(const uint4*)(kb + (kt + 1) * 2048 + soG);
            vrn = *(const uint4*)(vb + (kt + 1) * 2048 + soG);
        }
        bf16x8 kc[4], vf[4];
#pragma unroll
        for (int g = 0; g < 4; ++g) {
            kc[g] = *(const bf16x8*)&ks[cur][g * 16 * LROW + foff];
            vf[g] = *(const bf16x8*)&vs[cur][g * 16 * LROW + foff];
        }
#pragma unroll
        for (int qi = 0; qi < 2; ++qi) {
            f32x4 s[4];
#pragma unroll
            for (int g = 0; g < 4; ++g)
                s[g] = __builtin_amdgcn_mfma_f32_16x16x32_bf16(kc[g], qf[qi], zero, 0, 0, 0);
            float p[16];
#pragma unroll
            for (int g = 0; g < 4; ++g)
#pragma unroll
                for (int r = 0; r < 4; ++r)
                    p[g * 4 + r] = EXP2(s[g][r]);
            union { unsigned u[4]; bf16x8 v; } P0, P1;
            P0.u[0] = pk2t(p[0], p[1]);   P0.u[1] = pk2t(p[2], p[3]);
            P0.u[2] = pk2t(p[4], p[5]);   P0.u[3] = pk2t(p[6], p[7]);
            P1.u[0] = pk2t(p[8], p[9]);   P1.u[1] = pk2t(p[10], p[11]);
            P1.u[2] = pk2t(p[12], p[13]); P1.u[3] = pk2t(p[14], p[15]);
            acc0[qi] = __builtin_amdgcn_mfma_f32_16x16x32_bf16(vf[0], P0.v, acc0[qi], 0, 0, 0);
            acc1[qi] = __builtin_amdgcn_mfma_f32_16x16x32_bf16(vf[1], P0.v, acc1[qi], 0, 0, 0);
            accl[qi] = __builtin_amdgcn_mfma_f32_16x16x32_bf16(ones,  P0.v, accl[qi], 0, 0, 0);
            acc0[qi] = __builtin_amdgcn_mfma_f32_16x16x32_bf16(vf[2], P1.v, acc0[qi], 0, 0, 0);
            acc1[qi] = __builtin_amdgcn_mfma_f32_16x16x32_bf16(vf[3], P1.v, acc1[qi], 0, 0, 0);
            accl[qi] = __builtin_amdgcn_mfma_f32_16x16x32_bf16(ones,  P1.v, accl[qi], 0, 0, 0);
        }
        if (more) {
            *(uint4*)&ks[cur ^ 1][soW] = krn;
            *(uint4*)&vs[cur ^ 1][soW] = vrn;
        }
        __syncthreads();   // seals tile-(kt+1) writes; all reads of cur done
    }

    const int b = bh >> 3, hh = bh & 7;
#pragma unroll
    for (int qi = 0; qi < 2; ++qi) {
        const float inv = 1.f / accl[qi][0];   // full-key sum, identical in all regs
        const int t = q0 + qi * 16 + col;
        short* crow = cp + ((size_t)b * TP + t + 1) * CDIM + hh * DDIM;
        uint2 u0 = make_uint2(pk2(acc0[qi][0] * inv, acc0[qi][1] * inv),
                              pk2(acc0[qi][2] * inv, acc0[qi][3] * inv));
        uint2 u1 = make_uint2(pk2(acc1[qi][0] * inv, acc1[qi][1] * inv),
                              pk2(acc1[qi][2] * inv, acc1[qi][3] * inv));
        *(uint2*)(crow + quad * 4)      = u0;
        *(uint2*)(crow + 16 + quad * 4) = u1;
    }
}

// ---------------------------------------------------------------------------
extern "C" void kernel_launch(void* const* d_in, const int* in_sizes, int n_in,
                              void* d_out, int out_size, void* d_ws, size_t ws_size,
                              hipStream_t stream) {
    const float* x  = (const float*)d_in[0];
    const float* Wq = (const float*)d_in[1];
    const float* bq = (const float*)d_in[2];
    const float* Wk = (const float*)d_in[3];
    const float* bk = (const float*)d_in[4];
    const float* Wv = (const float*)d_in[5];
    const float* bv = (const float*)d_in[6];
    const float* Wo = (const float*)d_in[7];
    const float* bo = (const float*)d_in[8];
    float* out = (float*)d_out;

    short* p = (short*)d_ws;
    short* xbfp = p; p += (size_t)BDIM * TP * CDIM;        // 4,198,400
    short* cpb  = p; p += (size_t)BDIM * TP * CDIM;        // 4,198,400
    short* qbuf = p; p += (size_t)BDIM * HDIM * TDIM * DDIM; // 4,194,304
    short* kbuf = p; p += (size_t)BDIM * HDIM * TDIM * DDIM;
    short* vt2  = p; p += (size_t)BDIM * HDIM * TDIM * DDIM;
    short* wcat = p; p += 768 * 768;
    short* wot  = p; p += 256 * 768;
    // total ~43.5 MB

    prep_kernel<<<dim3(XBLK + WBLK), 256, 0, stream>>>(x, Wq, Wk, Wv, Wo, xbfp, cpb, wcat, wot);
    gemm_qkv<<<dim3(128, 6), 256, 0, stream>>>(xbfp, wcat, bq, bk, bv, qbuf, kbuf, vt2);
    attn_kernel<<<dim3(64, 16), 256, 0, stream>>>(qbuf, kbuf, vt2, cpb);
    gemm_res<<<dim3(128, 2), 256, 0, stream>>>(cpb, wot, bo, x, out);
}